// Round 2
// baseline (131.328 us; speedup 1.0000x reference)
//
#include <hip/hip_runtime.h>

#define BB 64
#define NN 512
#define DD 3
#define EPSF 1e-7f

// d_ws layout (floats): [0,B) = n per sample, [B,2B) = coord SE, [2B,3B) = edge BCE sum

__global__ __launch_bounds__(256) void prep_kernel(const float* __restrict__ pc,
                                                   const float* __restrict__ pts,
                                                   const int* __restrict__ masks,
                                                   float* __restrict__ ws) {
    const int b = blockIdx.x;
    const int tid = threadIdx.x;

    // count masked nodes
    int cnt = 0;
    for (int i = tid; i < NN; i += 256) cnt += masks[b * NN + i];

    // masked squared coordinate error over all N*D elements
    float se = 0.f;
    const float* pcb = pc + (size_t)b * NN * DD;
    const float* ptb = pts + (size_t)b * NN * DD;
    for (int e = tid; e < NN * DD; e += 256) {
        const int i = e / DD;
        const float m = (float)masks[b * NN + i];
        const float d = pcb[e] - ptb[e];
        se += d * d * m;
    }

    __shared__ float s_se[256];
    __shared__ int   s_cnt[256];
    s_se[tid] = se;
    s_cnt[tid] = cnt;
    __syncthreads();
    for (int off = 128; off > 0; off >>= 1) {
        if (tid < off) {
            s_se[tid]  += s_se[tid + off];
            s_cnt[tid] += s_cnt[tid + off];
        }
        __syncthreads();
    }
    if (tid == 0) {
        ws[b]          = (float)s_cnt[0];
        ws[BB + b]     = s_se[0];
        ws[2 * BB + b] = 0.f;   // init edge accumulator (ws is poisoned by harness)
    }
}

__global__ __launch_bounds__(128) void edge_kernel(const float* __restrict__ am,
                                                   const float* __restrict__ adj,
                                                   float* __restrict__ ws) {
    const int row = blockIdx.x;
    const int b   = blockIdx.y;
    const int n   = (int)ws[b];
    if (row >= n) return;

    const int tid = threadIdx.x;
    const size_t rbase = ((size_t)b * NN + row) * NN;
    const float4* amr = (const float4*)(am + rbase);
    const float4* adr = (const float4*)(adj + rbase);

    float sum = 0.f;
    const int j0 = tid * 4;
    if (j0 < n) {
        const float4 p4 = amr[tid];
        const float4 a4 = adr[tid];
        const float pv[4] = {p4.x, p4.y, p4.z, p4.w};
        const float av[4] = {a4.x, a4.y, a4.z, a4.w};
#pragma unroll
        for (int k = 0; k < 4; ++k) {
            if (j0 + k < n) {
                const float p = fminf(fmaxf(pv[k], EPSF), 1.f - EPSF);
                // a is exactly 0.0 or 1.0 -> a*log(p)+(1-a)*log1p(-p) == log(a?p:1-p)
                const float q = (av[k] != 0.f) ? p : (1.f - p);
                sum -= __logf(q);
            }
        }
    }

    __shared__ float sd[128];
    sd[tid] = sum;
    __syncthreads();
    for (int off = 64; off > 0; off >>= 1) {
        if (tid < off) sd[tid] += sd[tid + off];
        __syncthreads();
    }
    if (tid == 0) atomicAdd(ws + 2 * BB + b, sd[0]);
}

__global__ __launch_bounds__(64) void final_kernel(const float* __restrict__ ws,
                                                   const float* __restrict__ counts,
                                                   float* __restrict__ out) {
    const int tid = threadIdx.x;  // 64 threads == B samples
    const float n  = ws[tid];
    const float se = ws[BB + tid];
    const float es = ws[2 * BB + tid];

    const float coord_b = se / fmaxf(n * (float)DD, 1.f);
    const float edge_b  = es / fmaxf(n * n, 1.f);
    const float valid   = (n > 0.f) ? 1.f : 0.f;
    const float dc      = counts[tid] - n;

    float v0 = valid;
    float v1 = coord_b * valid;
    float v2 = edge_b * valid;
    float v3 = dc * dc;
    for (int off = 32; off > 0; off >>= 1) {
        v0 += __shfl_down(v0, off);
        v1 += __shfl_down(v1, off);
        v2 += __shfl_down(v2, off);
        v3 += __shfl_down(v3, off);
    }
    if (tid == 0) {
        const float vc = v0;
        const float denom = fmaxf(vc, 1.f);
        const float coord_loss = (vc > 0.f) ? (v1 / denom) : 0.f;
        const float edge_loss  = (vc > 0.f) ? (v2 / denom) : 0.f;
        const float count_loss = v3 / (float)BB;
        out[0] = coord_loss + edge_loss + 0.1f * count_loss;  // total
        out[1] = coord_loss;
        out[2] = edge_loss;
        out[3] = count_loss;
    }
}

extern "C" void kernel_launch(void* const* d_in, const int* in_sizes, int n_in,
                              void* d_out, int out_size, void* d_ws, size_t ws_size,
                              hipStream_t stream) {
    const float* pc    = (const float*)d_in[0];  // predicted_coords [B,N,D]
    const float* am    = (const float*)d_in[1];  // adjacency_matrix [B,N,N]
    const float* nc    = (const float*)d_in[2];  // node_counts [B,1]
    const float* pts   = (const float*)d_in[3];  // points [B,N,D]
    const float* adj   = (const float*)d_in[4];  // adjacency [B,N,N]
    const int*   masks = (const int*)d_in[5];    // node_masks [B,N]
    float* ws  = (float*)d_ws;
    float* out = (float*)d_out;

    prep_kernel<<<BB, 256, 0, stream>>>(pc, pts, masks, ws);
    dim3 egrid(NN, BB);
    edge_kernel<<<egrid, 128, 0, stream>>>(am, adj, ws);
    final_kernel<<<1, 64, 0, stream>>>(ws, nc, out);
}

// Round 4
// 29.417 us; speedup vs baseline: 4.4643x; 4.4643x over previous
//
#include <hip/hip_runtime.h>

#define BB 64
#define NN 512
#define DD 3
#define EPSF 1e-7f
#define ROWSPLIT 32

// d_ws layout (floats): [0,B) = n per sample, [B,2B) = coord SE, [2B,3B) = edge BCE sum

__global__ __launch_bounds__(256) void prep_kernel(const float* __restrict__ pc,
                                                   const float* __restrict__ pts,
                                                   const int* __restrict__ masks,
                                                   float* __restrict__ ws) {
    const int b = blockIdx.x;
    const int tid = threadIdx.x;

    // count masked nodes
    int cnt = 0;
    for (int i = tid; i < NN; i += 256) cnt += masks[b * NN + i];

    // masked squared coordinate error over all N*D elements
    float se = 0.f;
    const float* pcb = pc + (size_t)b * NN * DD;
    const float* ptb = pts + (size_t)b * NN * DD;
    for (int e = tid; e < NN * DD; e += 256) {
        const int i = e / DD;
        const float m = (float)masks[b * NN + i];
        const float d = pcb[e] - ptb[e];
        se += d * d * m;
    }

    __shared__ float s_se[256];
    __shared__ int   s_cnt[256];
    s_se[tid] = se;
    s_cnt[tid] = cnt;
    __syncthreads();
    for (int off = 128; off > 0; off >>= 1) {
        if (tid < off) {
            s_se[tid]  += s_se[tid + off];
            s_cnt[tid] += s_cnt[tid + off];
        }
        __syncthreads();
    }
    if (tid == 0) {
        ws[b]          = (float)s_cnt[0];
        ws[BB + b]     = s_se[0];
        ws[2 * BB + b] = 0.f;   // init edge accumulator (ws is poisoned by harness)
    }
}

// grid (ROWSPLIT, B), 128 threads. Each block handles rows {bx, bx+32, ...} < n
// of sample b, accumulating the BCE sum in registers, then one reduce + atomic.
__global__ __launch_bounds__(128) void edge_kernel(const float* __restrict__ am,
                                                   const float* __restrict__ adj,
                                                   float* __restrict__ ws) {
    const int b   = blockIdx.y;
    const int n   = (int)ws[b];
    const int tid = threadIdx.x;
    const int j0  = tid * 4;

    float sum = 0.f;
    if (j0 < n) {
        const size_t bbase = (size_t)b * NN * NN;
        for (int row = blockIdx.x; row < n; row += ROWSPLIT) {
            const float4* amr = (const float4*)(am + bbase + (size_t)row * NN);
            const float4* adr = (const float4*)(adj + bbase + (size_t)row * NN);
            const float4 p4 = amr[tid];
            const float4 a4 = adr[tid];
            const float pv[4] = {p4.x, p4.y, p4.z, p4.w};
            const float av[4] = {a4.x, a4.y, a4.z, a4.w};
#pragma unroll
            for (int k = 0; k < 4; ++k) {
                if (j0 + k < n) {
                    const float p = fminf(fmaxf(pv[k], EPSF), 1.f - EPSF);
                    // a is exactly 0.0 or 1.0 -> a*log(p)+(1-a)*log1p(-p) == log(a?p:1-p)
                    const float q = (av[k] != 0.f) ? p : (1.f - p);
                    sum -= __logf(q);
                }
            }
        }
    }

    __shared__ float sd[128];
    sd[tid] = sum;
    __syncthreads();
    for (int off = 64; off > 0; off >>= 1) {
        if (tid < off) sd[tid] += sd[tid + off];
        __syncthreads();
    }
    if (tid == 0) atomicAdd(ws + 2 * BB + b, sd[0]);
}

__global__ __launch_bounds__(64) void final_kernel(const float* __restrict__ ws,
                                                   const float* __restrict__ counts,
                                                   float* __restrict__ out) {
    const int tid = threadIdx.x;  // 64 threads == B samples
    const float n  = ws[tid];
    const float se = ws[BB + tid];
    const float es = ws[2 * BB + tid];

    const float coord_b = se / fmaxf(n * (float)DD, 1.f);
    const float edge_b  = es / fmaxf(n * n, 1.f);
    const float valid   = (n > 0.f) ? 1.f : 0.f;
    const float dc      = counts[tid] - n;

    float v0 = valid;
    float v1 = coord_b * valid;
    float v2 = edge_b * valid;
    float v3 = dc * dc;
    for (int off = 32; off > 0; off >>= 1) {
        v0 += __shfl_down(v0, off);
        v1 += __shfl_down(v1, off);
        v2 += __shfl_down(v2, off);
        v3 += __shfl_down(v3, off);
    }
    if (tid == 0) {
        const float vc = v0;
        const float denom = fmaxf(vc, 1.f);
        const float coord_loss = (vc > 0.f) ? (v1 / denom) : 0.f;
        const float edge_loss  = (vc > 0.f) ? (v2 / denom) : 0.f;
        const float count_loss = v3 / (float)BB;
        out[0] = coord_loss + edge_loss + 0.1f * count_loss;  // total
        out[1] = coord_loss;
        out[2] = edge_loss;
        out[3] = count_loss;
    }
}

extern "C" void kernel_launch(void* const* d_in, const int* in_sizes, int n_in,
                              void* d_out, int out_size, void* d_ws, size_t ws_size,
                              hipStream_t stream) {
    const float* pc    = (const float*)d_in[0];  // predicted_coords [B,N,D]
    const float* am    = (const float*)d_in[1];  // adjacency_matrix [B,N,N]
    const float* nc    = (const float*)d_in[2];  // node_counts [B,1]
    const float* pts   = (const float*)d_in[3];  // points [B,N,D]
    const float* adj   = (const float*)d_in[4];  // adjacency [B,N,N]
    const int*   masks = (const int*)d_in[5];    // node_masks [B,N]
    float* ws  = (float*)d_ws;
    float* out = (float*)d_out;

    prep_kernel<<<BB, 256, 0, stream>>>(pc, pts, masks, ws);
    dim3 egrid(ROWSPLIT, BB);
    edge_kernel<<<egrid, 128, 0, stream>>>(am, adj, ws);
    final_kernel<<<1, 64, 0, stream>>>(ws, nc, out);
}

// Round 5
// 23.152 us; speedup vs baseline: 5.6725x; 1.2706x over previous
//
#include <hip/hip_runtime.h>

#define BB 64
#define NN 512
#define DD 3
#define EPSF 1e-7f
#define SPLIT 64   // blocks per sample in x; 4096 blocks total -> exceeds residency, greedy balance

// ws (floats):
//   [0 .. BB*SPLIT)        edge BCE partial per (b, x)   -- written unconditionally by every block
//   [BB*SPLIT .. +BB)      n per sample                  -- written by (0, b)
//   [BB*SPLIT+BB .. +2BB)  coord SE per sample           -- written by (0, b)
#define WS_EDGE 0
#define WS_N    (BB * SPLIT)
#define WS_SE   (BB * SPLIT + BB)

__global__ __launch_bounds__(256) void fused_kernel(const float* __restrict__ am,
                                                    const float* __restrict__ adj,
                                                    const float* __restrict__ pc,
                                                    const float* __restrict__ pts,
                                                    const int* __restrict__ masks,
                                                    float* __restrict__ ws) {
    const int bx  = blockIdx.x;
    const int b   = blockIdx.y;
    const int tid = threadIdx.x;

    __shared__ float sdf[256];
    __shared__ int   sdi[256];
    __shared__ int   s_n;

    // ---- n = sum of prefix mask (each block computes locally; 2 KB, L2-served) ----
    const int2 mv = ((const int2*)(masks + b * NN))[tid];   // 256 thr x 2 ints = 512
    sdi[tid] = mv.x + mv.y;
    __syncthreads();
    for (int off = 128; off > 0; off >>= 1) {
        if (tid < off) sdi[tid] += sdi[tid + off];
        __syncthreads();
    }
    if (tid == 0) s_n = sdi[0];
    __syncthreads();
    const int n = s_n;

    // ---- coord SE + per-sample scalars (bx==0 blocks only) ----
    if (bx == 0) {
        const float* pcb = pc  + b * (NN * DD);
        const float* ptb = pts + b * (NN * DD);
        float se = 0.f;
        for (int e = tid; e < NN * DD; e += 256) {
            const int i = e / DD;                 // node index; prefix mask == (i < n)
            if (i < n) {
                const float d = pcb[e] - ptb[e];
                se += d * d;
            }
        }
        sdf[tid] = se;
        __syncthreads();
        for (int off = 128; off > 0; off >>= 1) {
            if (tid < off) sdf[tid] += sdf[tid + off];
            __syncthreads();
        }
        if (tid == 0) {
            ws[WS_N + b]  = (float)n;
            ws[WS_SE + b] = sdf[0];
        }
        __syncthreads();   // sdf reused below
    }

    // ---- edge BCE partial: 2 half-waves each cover one row's 512 floats ----
    const int half    = tid >> 7;        // 0 or 1
    const int lane128 = tid & 127;
    const int j0      = lane128 * 4;
    float sum = 0.f;
    if (j0 < n) {
        const size_t bbase = (size_t)b * NN * NN;
        for (int row = bx + half * SPLIT; row < n; row += 2 * SPLIT) {
            const float4 p4 = *(const float4*)(am  + bbase + (size_t)row * NN + j0);
            const float4 a4 = *(const float4*)(adj + bbase + (size_t)row * NN + j0);
            const float pv[4] = {p4.x, p4.y, p4.z, p4.w};
            const float av[4] = {a4.x, a4.y, a4.z, a4.w};
#pragma unroll
            for (int k = 0; k < 4; ++k) {
                if (j0 + k < n) {
                    const float p = fminf(fmaxf(pv[k], EPSF), 1.f - EPSF);
                    // a is exactly 0.0 or 1.0 -> a*log(p)+(1-a)*log1p(-p) == log(a?p:1-p)
                    const float q = (av[k] != 0.f) ? p : (1.f - p);
                    sum -= __logf(q);
                }
            }
        }
    }
    sdf[tid] = sum;
    __syncthreads();
    for (int off = 128; off > 0; off >>= 1) {
        if (tid < off) sdf[tid] += sdf[tid + off];
        __syncthreads();
    }
    if (tid == 0) ws[WS_EDGE + b * SPLIT + bx] = sdf[0];   // unconditional, deterministic
}

__global__ __launch_bounds__(64) void final_kernel(const float* __restrict__ ws,
                                                   const float* __restrict__ counts,
                                                   float* __restrict__ out) {
    const int b = threadIdx.x;   // 64 threads == B samples

    // sum this sample's SPLIT edge partials (16 x float4)
    const float4* ep = (const float4*)(ws + WS_EDGE + b * SPLIT);
    float es = 0.f;
#pragma unroll
    for (int k = 0; k < SPLIT / 4; ++k) {
        const float4 v = ep[k];
        es += v.x + v.y + v.z + v.w;
    }

    const float n  = ws[WS_N + b];
    const float se = ws[WS_SE + b];

    const float coord_b = se / fmaxf(n * (float)DD, 1.f);
    const float edge_b  = es / fmaxf(n * n, 1.f);
    const float valid   = (n > 0.f) ? 1.f : 0.f;
    const float dc      = counts[b] - n;

    float v0 = valid;
    float v1 = coord_b * valid;
    float v2 = edge_b * valid;
    float v3 = dc * dc;
    for (int off = 32; off > 0; off >>= 1) {
        v0 += __shfl_down(v0, off);
        v1 += __shfl_down(v1, off);
        v2 += __shfl_down(v2, off);
        v3 += __shfl_down(v3, off);
    }
    if (b == 0) {
        const float vc = v0;
        const float denom = fmaxf(vc, 1.f);
        const float coord_loss = (vc > 0.f) ? (v1 / denom) : 0.f;
        const float edge_loss  = (vc > 0.f) ? (v2 / denom) : 0.f;
        const float count_loss = v3 / (float)BB;
        out[0] = coord_loss + edge_loss + 0.1f * count_loss;  // total
        out[1] = coord_loss;
        out[2] = edge_loss;
        out[3] = count_loss;
    }
}

extern "C" void kernel_launch(void* const* d_in, const int* in_sizes, int n_in,
                              void* d_out, int out_size, void* d_ws, size_t ws_size,
                              hipStream_t stream) {
    const float* pc    = (const float*)d_in[0];  // predicted_coords [B,N,D]
    const float* am    = (const float*)d_in[1];  // adjacency_matrix [B,N,N]
    const float* nc    = (const float*)d_in[2];  // node_counts [B,1]
    const float* pts   = (const float*)d_in[3];  // points [B,N,D]
    const float* adj   = (const float*)d_in[4];  // adjacency [B,N,N]
    const int*   masks = (const int*)d_in[5];    // node_masks [B,N]
    float* ws  = (float*)d_ws;
    float* out = (float*)d_out;

    dim3 grid(SPLIT, BB);
    fused_kernel<<<grid, 256, 0, stream>>>(am, adj, pc, pts, masks, ws);
    final_kernel<<<1, 64, 0, stream>>>(ws, nc, out);
}

// Round 6
// 21.475 us; speedup vs baseline: 6.1154x; 1.0781x over previous
//
#include <hip/hip_runtime.h>

#define BB 64
#define NN 512
#define DD 3
#define EPSF 1e-7f
#define SPLIT 64   // blocks per sample in x; 4096 blocks total

// ws (floats):
//   [0 .. BB*SPLIT)        edge BCE partial per (b, x)   -- written unconditionally by every block
//   [BB*SPLIT .. +BB)      n per sample                  -- written by (0, b)
//   [BB*SPLIT+BB .. +2BB)  coord SE per sample           -- written by (0, b)
#define WS_EDGE 0
#define WS_N    (BB * SPLIT)
#define WS_SE   (BB * SPLIT + BB)

__global__ __launch_bounds__(256) void fused_kernel(const float* __restrict__ am,
                                                    const float* __restrict__ adj,
                                                    const float* __restrict__ pc,
                                                    const float* __restrict__ pts,
                                                    const int* __restrict__ masks,
                                                    float* __restrict__ ws) {
    const int bx  = blockIdx.x;
    const int b   = blockIdx.y;
    const int tid = threadIdx.x;

    __shared__ int   s_n;
    __shared__ float s_part[4];
    __shared__ float s_cpart[4];

    // ---- n via prefix-boundary detection: exactly one thread sees the 1->0 edge ----
    const int2 mv = ((const int2*)(masks + b * NN))[tid];        // positions 2tid, 2tid+1
    const int  nxt = (tid < 255) ? masks[b * NN + 2 * tid + 2] : 0;
    if (tid == 0 && mv.x == 0) s_n = 0;
    if (mv.x == 1 && mv.y == 0) s_n = 2 * tid + 1;
    if (mv.y == 1 && nxt == 0)  s_n = 2 * tid + 2;
    __syncthreads();
    const int n = s_n;

    const int wid  = tid >> 6;
    const int lane = tid & 63;

    // ---- coord SE + per-sample scalars (bx==0 blocks only) ----
    if (bx == 0) {
        const float* pcb = pc  + b * (NN * DD);
        const float* ptb = pts + b * (NN * DD);
        float se = 0.f;
        for (int e = tid; e < NN * DD; e += 256) {
            if (e < n * DD) {                    // prefix mask: node e/DD valid iff e < n*DD
                const float d = pcb[e] - ptb[e];
                se += d * d;
            }
        }
#pragma unroll
        for (int off = 32; off; off >>= 1) se += __shfl_xor(se, off);
        if (lane == 0) s_cpart[wid] = se;
    }

    // ---- edge BCE partial: 2 half-waves each cover one row's 512 floats ----
    const int half    = tid >> 7;        // 0 or 1
    const int lane128 = tid & 127;
    const int j0      = lane128 * 4;
    float sum = 0.f;
    if (j0 < n) {
        const size_t bbase = (size_t)b * NN * NN;
        for (int row = bx + half * SPLIT; row < n; row += 2 * SPLIT) {
            const float4 p4 = *(const float4*)(am  + bbase + (size_t)row * NN + j0);
            const float4 a4 = *(const float4*)(adj + bbase + (size_t)row * NN + j0);
            const float pv[4] = {p4.x, p4.y, p4.z, p4.w};
            const float av[4] = {a4.x, a4.y, a4.z, a4.w};
#pragma unroll
            for (int k = 0; k < 4; ++k) {
                if (j0 + k < n) {
                    const float p = fminf(fmaxf(pv[k], EPSF), 1.f - EPSF);
                    // a is exactly 0.0 or 1.0 -> a*log(p)+(1-a)*log1p(-p) == log(a?p:1-p)
                    const float q = (av[k] != 0.f) ? p : (1.f - p);
                    sum -= __logf(q);
                }
            }
        }
    }
#pragma unroll
    for (int off = 32; off; off >>= 1) sum += __shfl_xor(sum, off);
    if (lane == 0) s_part[wid] = sum;
    __syncthreads();

    if (tid == 0) {
        ws[WS_EDGE + b * SPLIT + bx] = s_part[0] + s_part[1] + s_part[2] + s_part[3];
        if (bx == 0) {
            ws[WS_N + b]  = (float)n;
            ws[WS_SE + b] = s_cpart[0] + s_cpart[1] + s_cpart[2] + s_cpart[3];
        }
    }
}

__global__ __launch_bounds__(64) void final_kernel(const float* __restrict__ ws,
                                                   const float* __restrict__ counts,
                                                   float* __restrict__ out) {
    const int b = threadIdx.x;   // 64 threads == B samples

    // sum this sample's SPLIT edge partials (16 x float4)
    const float4* ep = (const float4*)(ws + WS_EDGE + b * SPLIT);
    float es = 0.f;
#pragma unroll
    for (int k = 0; k < SPLIT / 4; ++k) {
        const float4 v = ep[k];
        es += v.x + v.y + v.z + v.w;
    }

    const float n  = ws[WS_N + b];
    const float se = ws[WS_SE + b];

    const float coord_b = se / fmaxf(n * (float)DD, 1.f);
    const float edge_b  = es / fmaxf(n * n, 1.f);
    const float valid   = (n > 0.f) ? 1.f : 0.f;
    const float dc      = counts[b] - n;

    float v0 = valid;
    float v1 = coord_b * valid;
    float v2 = edge_b * valid;
    float v3 = dc * dc;
    for (int off = 32; off > 0; off >>= 1) {
        v0 += __shfl_down(v0, off);
        v1 += __shfl_down(v1, off);
        v2 += __shfl_down(v2, off);
        v3 += __shfl_down(v3, off);
    }
    if (b == 0) {
        const float vc = v0;
        const float denom = fmaxf(vc, 1.f);
        const float coord_loss = (vc > 0.f) ? (v1 / denom) : 0.f;
        const float edge_loss  = (vc > 0.f) ? (v2 / denom) : 0.f;
        const float count_loss = v3 / (float)BB;
        out[0] = coord_loss + edge_loss + 0.1f * count_loss;  // total
        out[1] = coord_loss;
        out[2] = edge_loss;
        out[3] = count_loss;
    }
}

extern "C" void kernel_launch(void* const* d_in, const int* in_sizes, int n_in,
                              void* d_out, int out_size, void* d_ws, size_t ws_size,
                              hipStream_t stream) {
    const float* pc    = (const float*)d_in[0];  // predicted_coords [B,N,D]
    const float* am    = (const float*)d_in[1];  // adjacency_matrix [B,N,N]
    const float* nc    = (const float*)d_in[2];  // node_counts [B,1]
    const float* pts   = (const float*)d_in[3];  // points [B,N,D]
    const float* adj   = (const float*)d_in[4];  // adjacency [B,N,N]
    const int*   masks = (const int*)d_in[5];    // node_masks [B,N]
    float* ws  = (float*)d_ws;
    float* out = (float*)d_out;

    dim3 grid(SPLIT, BB);
    fused_kernel<<<grid, 256, 0, stream>>>(am, adj, pc, pts, masks, ws);
    final_kernel<<<1, 64, 0, stream>>>(ws, nc, out);
}